// Round 21
// baseline (63.126 us; speedup 1.0000x reference)
//
#include <hip/hip_runtime.h>
#include <math.h>

#define T_LEN      24000
#define W_LEN      81
#define HALF_W     40
#define NK         21
#define MAXORD     10
#define NIMG_TOTAL 1561
#define NROUNDS    25            // ceil(1561/64)
#define NB         376           // t0 bins of width 64 (t0 <= 24039)
#define GSAMP      256           // output samples per gather block
#define NGRP       94            // ceil(24000/256)
#define FS_F       48000.0f
#define C_F        343.0f
#define FS_OVER_C  (48000.0f / 343.0f)
#define C_OVER_FS  (343.0f / 48000.0f)
#define PI_F       3.14159265358979323846f
#define HSTEP      (2.0f * PI_F / 80.0f)
#define INV_4PI_F  0.07957747154594767f
#define LOG2_BETA  (-0.15200309344504997f)   // log2(0.9)
#define NEG_SLOPE  0.01f

// ws row: 384 ints hdr (377 used) + 1600 float4 params
#define HDR_I      384
#define ROW_BYTES  (HDR_I * 4 + 1600 * 16)   // 27136 B

struct Table { unsigned int e[NROUNDS * 64]; };
constexpr Table make_table() {
    Table t{};
    int n = 0;
    for (int kx = 0; kx < NK; ++kx)
        for (int ky = 0; ky < NK; ++ky)
            for (int kz = 0; kz < NK; ++kz) {
                int ax = kx >= MAXORD ? kx - MAXORD : MAXORD - kx;
                int ay = ky >= MAXORD ? ky - MAXORD : MAXORD - ky;
                int az = kz >= MAXORD ? kz - MAXORD : MAXORD - kz;
                int order = ax + ay + az;
                if (order <= MAXORD)
                    t.e[n++] = (unsigned)((order << 15) | (kx << 10) | (ky << 5) | kz);
            }
    for (int i = n; i < NROUNDS * 64; ++i) t.e[i] = t.e[n - 1];
    return t;
}
__constant__ Table g_tbl = make_table();

// ===== Kernel 1: 8-wave per-row prep: MLP + geometry + bin-sorted params ====
__global__ __launch_bounds__(512)
void rir_prep_kernel(const float* __restrict__ g_in,
                     const float* __restrict__ W1, const float* __restrict__ b1,
                     const float* __restrict__ W2, const float* __restrict__ b2,
                     const float* __restrict__ W3, const float* __restrict__ b3,
                     unsigned char* __restrict__ ws, float* __restrict__ out_origin)
{
    __shared__ float dsq[3 * NK];
    __shared__ float h1[30], h2[20], zb[9], sm_in[22], rms[9];
    __shared__ float bp[MAXORD + 1];
    __shared__ float dlys[NROUNDS * 64];     // pass-1 delay cache (sentinel if dead)
    __shared__ int counts[NB], offs[NB + 1], cursor[NB];

    const int tid  = threadIdx.x;
    const int lane = tid & 63;
    const int w    = tid >> 6;               // 0..7
    const int b    = blockIdx.x;

    for (int i = tid; i < NB; i += 512) { counts[i] = 0; cursor[i] = 0; }

    // ---- wave 0: MLP + geometry; wave 1: beta-power table ----
    if (w == 1 && lane <= MAXORD)
        bp[lane] = exp2f((float)lane * LOG2_BETA) * INV_4PI_F;
    if (w == 0) {
        if (lane < 22) sm_in[lane] = g_in[b * 22 + lane];
        if (lane < 30) {
            float a = b1[lane];
            const float* wp = W1 + lane * 22;
            #pragma unroll
            for (int i = 0; i < 22; ++i) a += sm_in[i] * wp[i];
            h1[lane] = (a >= 0.0f) ? a : NEG_SLOPE * a;
        }
        if (lane < 20) {
            float a = b2[lane];
            const float* wp = W2 + lane * 30;
            #pragma unroll
            for (int i = 0; i < 30; ++i) a += h1[i] * wp[i];
            h2[lane] = (a >= 0.0f) ? a : NEG_SLOPE * a;
        }
        if (lane < 9) {
            float a = b3[lane];
            const float* wp = W3 + lane * 20;
            #pragma unroll
            for (int i = 0; i < 20; ++i) a += h2[i] * wp[i];
            zb[lane] = 1.0f / (1.0f + __expf(-a));
        }
        if (lane < 3) {
            float room = zb[lane] * 20.0f;
            rms[lane]     = room;
            rms[3 + lane] = zb[3 + lane] * room;   // mic
            rms[6 + lane] = zb[6 + lane] * room;   // src
        }
        if (lane == 0) {
            float dx = rms[3] - rms[6], dy = rms[4] - rms[7], dz = rms[5] - rms[8];
            out_origin[b] = 40.0f + FS_F * sqrtf(dx * dx + dy * dy + dz * dz) / C_F;
        }
        if (lane < 3 * NK) {
            int a  = lane / NK;
            int kk = (lane - a * NK) - MAXORD;
            float L = rms[a], src = rms[6 + a];
            float img = ((kk & 1) == 0) ? (float)kk * L + src : (float)(kk + 1) * L - src;
            float diff = img - rms[3 + a];
            dsq[lane] = diff * diff;
        }
    }
    __syncthreads();

    // ---- pass 1: compute delays once, bin counts; rounds split 8 ways ----
    for (int r = w; r < NROUNDS; r += 8) {
        int gi = r * 64 + lane;
        unsigned e = g_tbl.e[gi];
        int kzi = e & 31, kyi = (e >> 5) & 31, kxi = (e >> 10) & 31;
        float d   = sqrtf(dsq[kxi] + dsq[NK + kyi] + dsq[2 * NK + kzi]);
        float dly = 40.0f + d * FS_OVER_C;
        int   t0  = (int)floorf(dly);
        bool live = (gi < NIMG_TOTAL) && (t0 - HALF_W < T_LEN);   // t0 <= 24039
        dlys[gi] = live ? dly : 1.0e9f;
        if (live) atomicAdd(&counts[t0 >> 6], 1);
    }
    __syncthreads();

    // ---- exclusive scan over 376 bins: wave 0, 6 bins/lane + shfl scan ----
    if (w == 0) {
        const int base = lane * 6;
        int c[6], s0 = 0;
        #pragma unroll
        for (int j = 0; j < 6; ++j) {
            int idx = base + j;
            c[j] = (idx < NB) ? counts[idx] : 0;
            s0 += c[j];
        }
        int incl = s0;
        #pragma unroll
        for (int off = 1; off < 64; off <<= 1) {
            int t = __shfl_up(incl, off);
            if (lane >= off) incl += t;
        }
        int acc = incl - s0;
        #pragma unroll
        for (int j = 0; j < 6; ++j) {
            int idx = base + j;
            if (idx < NB) offs[idx] = acc;
            acc += c[j];
        }
        if (lane == 63) offs[NB] = acc;
    }
    __syncthreads();

    unsigned char* rowp = ws + (size_t)b * ROW_BYTES;
    int*    hdr  = (int*)rowp;
    float4* prow = (float4*)(rowp + HDR_I * 4);

    // ---- pass 2: params from cached delay (no sqrt/dsq), bin-sorted ----
    for (int r = w; r < NROUNDS; r += 8) {
        int gi = r * 64 + lane;
        float dly = dlys[gi];
        if (dly < 1.0e8f) {
            int order = (int)(g_tbl.e[gi] >> 15);
            float t0f  = floorf(dly);
            float frac = dly - t0f;
            float d    = (dly - 40.0f) * C_OVER_FS;
            float amp  = bp[order] * __builtin_amdgcn_rcpf(fmaxf(d, 0.001f));
            float sp   = __sinf(PI_F * frac);
            int bin  = (int)t0f;
            int rank = offs[bin >> 6] + atomicAdd(&cursor[bin >> 6], 1);
            prow[rank] = make_float4(amp * sp, frac, amp, t0f);
        }
    }
    __syncthreads();

    for (int i = tid; i <= NB; i += 512) hdr[i] = offs[i];
}

// ===== Kernel 2: gather — block owns 256 samples, 4 waves split images ======
__global__ __launch_bounds__(256)
void rir_gather256_kernel(const unsigned char* __restrict__ ws,
                          float* __restrict__ out_rir)
{
    __shared__ float buf[GSAMP];
    __shared__ float hann[W_LEN + 7];

    const int tid  = threadIdx.x;
    const int lane = tid & 63;
    const int w    = tid >> 6;
    const int grp  = blockIdx.x;
    const int b    = blockIdx.y;
    const int g0   = grp * GSAMP;

    const unsigned char* rowp = ws + (size_t)b * ROW_BYTES;
    const int*    hdr  = (const int*)rowp;
    const float4* prow = (const float4*)(rowp + HDR_I * 4);

    const int blo   = max(g0 - HALF_W, 0) >> 6;
    const int bhi   = min(g0 + GSAMP - 1 + HALF_W, T_LEN + HALF_W - 1) >> 6;  // <= 375
    const int start = hdr[blo];
    const int end   = hdr[bhi + 1];

    buf[tid] = 0.0f;
    if (tid >= 128 && tid < 128 + W_LEN)
        hann[tid - 128] = 0.5f - 0.5f * __cosf((float)(tid - 128) * HSTEP);
    __syncthreads();

    float acc[4] = {0.f, 0.f, 0.f, 0.f};
    const float gf0 = (float)(g0 + lane);       // slots at +0, +64, +128, +192

    #pragma unroll 2
    for (int i = start + w; i < end; i += 4) {
        float4 p = prow[i];                     // (asp, frac, amp, t0f)
        float n0 = gf0 - p.w;
        #pragma unroll
        for (int k = 0; k < 4; ++k) {
            float n = n0 + 64.0f * (float)k;
            if (fabsf(n) <= 40.0f) {            // <=2 of 4 can hit
                float x  = n - p.y;             // t - delay
                int   ni = (int)n;              // exact (n integer-valued)
                float sg = (ni & 1) ? p.x : -p.x;
                float v  = (x == 0.0f) ? p.z : sg * __builtin_amdgcn_rcpf(PI_F * x);
                acc[k] += v * hann[ni + HALF_W];
            }
        }
    }

    #pragma unroll
    for (int k = 0; k < 4; ++k)
        if (acc[k] != 0.0f) atomicAdd(&buf[lane + 64 * k], acc[k]);
    __syncthreads();

    const int g = g0 + tid;
    if (g < T_LEN)
        out_rir[(size_t)b * T_LEN + g] = buf[tid];
}

// ===== Fallback: R10 single-kernel (ws too small) ===========================
#define FTS 448
#define FNSLICE 54
__global__ __launch_bounds__(64)
void rir_wave_kernel(const float* __restrict__ g_in,
                     const float* __restrict__ W1, const float* __restrict__ b1,
                     const float* __restrict__ W2, const float* __restrict__ b2,
                     const float* __restrict__ W3, const float* __restrict__ b3,
                     float* __restrict__ out_rir, float* __restrict__ out_origin)
{
    __shared__ __align__(16) float rirw[FTS];
    __shared__ float dsq[3 * NK];
    __shared__ float h1[30], h2[20], zb[9], sm_in[22], rms[9];

    const int lane = threadIdx.x;
    const int s    = blockIdx.x;
    const int b    = blockIdx.y;
    const int lo   = s * FTS;
    const int nout = min(FTS, T_LEN - lo);

    float4* rir4 = (float4*)rirw;
    rir4[lane] = make_float4(0.f, 0.f, 0.f, 0.f);
    if (lane < FTS / 4 - 64) rir4[64 + lane] = make_float4(0.f, 0.f, 0.f, 0.f);

    const float c1p = PI_F * (float)(lane - HALF_W);
    const float hw1 = 0.5f - 0.5f * __cosf((float)lane * HSTEP);
    const float hw2 = 0.5f - 0.5f * __cosf((float)(lane + 64) * HSTEP);
    const float sg  = (lane & 1) ? 1.0f : -1.0f;

    if (lane < 22) sm_in[lane] = g_in[b * 22 + lane];
    if (lane < 30) {
        float a = b1[lane];
        const float* wp = W1 + lane * 22;
        #pragma unroll
        for (int i = 0; i < 22; ++i) a += sm_in[i] * wp[i];
        h1[lane] = (a >= 0.0f) ? a : NEG_SLOPE * a;
    }
    if (lane < 20) {
        float a = b2[lane];
        const float* wp = W2 + lane * 30;
        #pragma unroll
        for (int i = 0; i < 30; ++i) a += h1[i] * wp[i];
        h2[lane] = (a >= 0.0f) ? a : NEG_SLOPE * a;
    }
    if (lane < 9) {
        float a = b3[lane];
        const float* wp = W3 + lane * 20;
        #pragma unroll
        for (int i = 0; i < 20; ++i) a += h2[i] * wp[i];
        zb[lane] = 1.0f / (1.0f + __expf(-a));
    }
    if (lane < 3) {
        float room = zb[lane] * 20.0f;
        rms[lane]     = room;
        rms[3 + lane] = zb[3 + lane] * room;
        rms[6 + lane] = zb[6 + lane] * room;
    }
    if (lane == 0 && s == 0) {
        float dx = rms[3] - rms[6], dy = rms[4] - rms[7], dz = rms[5] - rms[8];
        out_origin[b] = 40.0f + FS_F * sqrtf(dx * dx + dy * dy + dz * dz) / C_F;
    }
    if (lane < 3 * NK) {
        int a  = lane / NK;
        int kk = (lane - a * NK) - MAXORD;
        float L = rms[a], src = rms[6 + a];
        float img = ((kk & 1) == 0) ? (float)kk * L + src : (float)(kk + 1) * L - src;
        float diff = img - rms[3 + a];
        dsq[lane] = diff * diff;
    }

    const float lof = (float)(lo - HALF_W);
    const float hif = (float)(lo + nout - 1 + HALF_W);

    for (int r = 0; r < NROUNDS; ++r) {
        unsigned e = g_tbl.e[r * 64 + lane];
        bool live  = (r * 64 + lane) < NIMG_TOTAL;
        int kzi = e & 31, kyi = (e >> 5) & 31, kxi = (e >> 10) & 31, order = (int)(e >> 15);
        float d    = sqrtf(dsq[kxi] + dsq[NK + kyi] + dsq[2 * NK + kzi]);
        float dlyv = 40.0f + d * FS_OVER_C;
        float t0f  = floorf(dlyv);
        float ampv = exp2f((float)order * LOG2_BETA) * INV_4PI_F
                     * __builtin_amdgcn_rcpf(fmaxf(d, 0.001f));
        bool hit = live && (t0f >= lof) && (t0f <= hif);

        unsigned long long mask = __ballot(hit);
        while (mask) {
            int l0 = __builtin_ctzll(mask); mask &= mask - 1;
            float a0 = __shfl(ampv, l0), d0 = __shfl(dlyv, l0);
            float t0b  = floorf(d0);
            float frac = d0 - t0b;
            float sp   = __sinf(PI_F * frac);
            float pv   = sg * sp;
            int   idx  = (int)t0b - HALF_W + lane - lo;
            float x1p  = c1p - PI_F * frac;
            float sv1  = (x1p == 0.0f) ? 1.0f : pv * __builtin_amdgcn_rcpf(x1p);
            if ((unsigned)idx < (unsigned)nout)
                atomicAdd(&rirw[idx], a0 * sv1 * hw1);
            if (lane < 17) {
                int idx2 = idx + 64;
                float sv2 = pv * __builtin_amdgcn_rcpf(x1p + 64.0f * PI_F);
                if ((unsigned)idx2 < (unsigned)nout)
                    atomicAdd(&rirw[idx2], a0 * sv2 * hw2);
            }
        }
    }

    const int n4 = nout / 4;
    float4* out4 = (float4*)(out_rir + (size_t)b * T_LEN + lo);
    out4[lane] = rir4[lane];
    if (lane + 64 < n4) out4[lane + 64] = rir4[lane + 64];
}

extern "C" void kernel_launch(void* const* d_in, const int* in_sizes, int n_in,
                              void* d_out, int out_size, void* d_ws, size_t ws_size,
                              hipStream_t stream) {
    const float* g_in = (const float*)d_in[0];
    const float* W1   = (const float*)d_in[1];
    const float* b1   = (const float*)d_in[2];
    const float* W2   = (const float*)d_in[3];
    const float* b2   = (const float*)d_in[4];
    const float* W3   = (const float*)d_in[5];
    const float* b3   = (const float*)d_in[6];

    const int B = in_sizes[0] / 22;

    float* out_rir    = (float*)d_out;
    float* out_origin = out_rir + (size_t)B * T_LEN;

    const size_t need_ws = (size_t)B * ROW_BYTES;   // ~3.47 MB @ B=128

    if (ws_size >= need_ws) {
        unsigned char* ws = (unsigned char*)d_ws;
        rir_prep_kernel<<<B, 512, 0, stream>>>(
            g_in, W1, b1, W2, b2, W3, b3, ws, out_origin);
        dim3 grid2(NGRP, B);
        rir_gather256_kernel<<<grid2, 256, 0, stream>>>(ws, out_rir);
    } else {
        dim3 grid(FNSLICE, B);
        rir_wave_kernel<<<grid, 64, 0, stream>>>(
            g_in, W1, b1, W2, b2, W3, b3, out_rir, out_origin);
    }
}

// Round 22
// 62.546 us; speedup vs baseline: 1.0093x; 1.0093x over previous
//
#include <hip/hip_runtime.h>
#include <math.h>

#define T_LEN      24000
#define W_LEN      81
#define HALF_W     40
#define NK         21
#define MAXORD     10
#define NIMG_TOTAL 1561
#define NROUNDS    25            // ceil(1561/64)
#define NB         376           // t0 bins of width 64 (t0 <= 24039)
#define GSAMP      256           // output samples per gather block
#define NGRP       94            // ceil(24000/256)
#define FS_F       48000.0f
#define C_F        343.0f
#define FS_OVER_C  (48000.0f / 343.0f)
#define C_OVER_FS  (343.0f / 48000.0f)
#define PI_F       3.14159265358979323846f
#define HSTEP      (2.0f * PI_F / 80.0f)
#define INV_4PI_F  0.07957747154594767f
#define LOG2_BETA  (-0.15200309344504997f)   // log2(0.9)
#define NEG_SLOPE  0.01f

// ws row: 384 ints hdr (377 used) + 1600 float4 params
#define HDR_I      384
#define ROW_BYTES  (HDR_I * 4 + 1600 * 16)   // 27136 B

struct Table { unsigned int e[NROUNDS * 64]; };
constexpr Table make_table() {
    Table t{};
    int n = 0;
    for (int kx = 0; kx < NK; ++kx)
        for (int ky = 0; ky < NK; ++ky)
            for (int kz = 0; kz < NK; ++kz) {
                int ax = kx >= MAXORD ? kx - MAXORD : MAXORD - kx;
                int ay = ky >= MAXORD ? ky - MAXORD : MAXORD - ky;
                int az = kz >= MAXORD ? kz - MAXORD : MAXORD - kz;
                int order = ax + ay + az;
                if (order <= MAXORD)
                    t.e[n++] = (unsigned)((order << 15) | (kx << 10) | (ky << 5) | kz);
            }
    for (int i = n; i < NROUNDS * 64; ++i) t.e[i] = t.e[n - 1];
    return t;
}
__constant__ Table g_tbl = make_table();

// ===== Kernel 1: 8-wave per-row prep: MLP + geometry + bin-sorted params ====
__global__ __launch_bounds__(512)
void rir_prep_kernel(const float* __restrict__ g_in,
                     const float* __restrict__ W1, const float* __restrict__ b1,
                     const float* __restrict__ W2, const float* __restrict__ b2,
                     const float* __restrict__ W3, const float* __restrict__ b3,
                     unsigned char* __restrict__ ws, float* __restrict__ out_origin)
{
    __shared__ float dsq[3 * NK];
    __shared__ float h1[30], h2[20], zb[9], sm_in[22], rms[9];
    __shared__ float bp[MAXORD + 1];
    __shared__ float dlys[NROUNDS * 64];     // pass-1 delay cache (sentinel if dead)
    __shared__ int counts[NB], offs[NB + 1], cursor[NB];

    const int tid  = threadIdx.x;
    const int lane = tid & 63;
    const int w    = tid >> 6;               // 0..7
    const int b    = blockIdx.x;

    for (int i = tid; i < NB; i += 512) { counts[i] = 0; cursor[i] = 0; }

    if (w == 1 && lane <= MAXORD)
        bp[lane] = exp2f((float)lane * LOG2_BETA) * INV_4PI_F;
    if (w == 0) {
        if (lane < 22) sm_in[lane] = g_in[b * 22 + lane];
        if (lane < 30) {
            float a = b1[lane];
            const float* wp = W1 + lane * 22;
            #pragma unroll
            for (int i = 0; i < 22; ++i) a += sm_in[i] * wp[i];
            h1[lane] = (a >= 0.0f) ? a : NEG_SLOPE * a;
        }
        if (lane < 20) {
            float a = b2[lane];
            const float* wp = W2 + lane * 30;
            #pragma unroll
            for (int i = 0; i < 30; ++i) a += h1[i] * wp[i];
            h2[lane] = (a >= 0.0f) ? a : NEG_SLOPE * a;
        }
        if (lane < 9) {
            float a = b3[lane];
            const float* wp = W3 + lane * 20;
            #pragma unroll
            for (int i = 0; i < 20; ++i) a += h2[i] * wp[i];
            zb[lane] = 1.0f / (1.0f + __expf(-a));
        }
        if (lane < 3) {
            float room = zb[lane] * 20.0f;
            rms[lane]     = room;
            rms[3 + lane] = zb[3 + lane] * room;   // mic
            rms[6 + lane] = zb[6 + lane] * room;   // src
        }
        if (lane == 0) {
            float dx = rms[3] - rms[6], dy = rms[4] - rms[7], dz = rms[5] - rms[8];
            out_origin[b] = 40.0f + FS_F * sqrtf(dx * dx + dy * dy + dz * dz) / C_F;
        }
        if (lane < 3 * NK) {
            int a  = lane / NK;
            int kk = (lane - a * NK) - MAXORD;
            float L = rms[a], src = rms[6 + a];
            float img = ((kk & 1) == 0) ? (float)kk * L + src : (float)(kk + 1) * L - src;
            float diff = img - rms[3 + a];
            dsq[lane] = diff * diff;
        }
    }
    __syncthreads();

    // pass 1: compute delays once, bin counts; rounds split 8 ways
    for (int r = w; r < NROUNDS; r += 8) {
        int gi = r * 64 + lane;
        unsigned e = g_tbl.e[gi];
        int kzi = e & 31, kyi = (e >> 5) & 31, kxi = (e >> 10) & 31;
        float d   = sqrtf(dsq[kxi] + dsq[NK + kyi] + dsq[2 * NK + kzi]);
        float dly = 40.0f + d * FS_OVER_C;
        int   t0  = (int)floorf(dly);
        bool live = (gi < NIMG_TOTAL) && (t0 - HALF_W < T_LEN);   // t0 <= 24039
        dlys[gi] = live ? dly : 1.0e9f;
        if (live) atomicAdd(&counts[t0 >> 6], 1);
    }
    __syncthreads();

    // exclusive scan over 376 bins: wave 0, 6 bins/lane + shfl scan
    if (w == 0) {
        const int base = lane * 6;
        int c[6], s0 = 0;
        #pragma unroll
        for (int j = 0; j < 6; ++j) {
            int idx = base + j;
            c[j] = (idx < NB) ? counts[idx] : 0;
            s0 += c[j];
        }
        int incl = s0;
        #pragma unroll
        for (int off = 1; off < 64; off <<= 1) {
            int t = __shfl_up(incl, off);
            if (lane >= off) incl += t;
        }
        int acc = incl - s0;
        #pragma unroll
        for (int j = 0; j < 6; ++j) {
            int idx = base + j;
            if (idx < NB) offs[idx] = acc;
            acc += c[j];
        }
        if (lane == 63) offs[NB] = acc;
    }
    __syncthreads();

    unsigned char* rowp = ws + (size_t)b * ROW_BYTES;
    int*    hdr  = (int*)rowp;
    float4* prow = (float4*)(rowp + HDR_I * 4);

    // pass 2: params from cached delay (no sqrt/dsq), bin-sorted
    for (int r = w; r < NROUNDS; r += 8) {
        int gi = r * 64 + lane;
        float dly = dlys[gi];
        if (dly < 1.0e8f) {
            int order = (int)(g_tbl.e[gi] >> 15);
            float t0f  = floorf(dly);
            float frac = dly - t0f;
            float d    = (dly - 40.0f) * C_OVER_FS;
            float amp  = bp[order] * __builtin_amdgcn_rcpf(fmaxf(d, 0.001f));
            float sp   = __sinf(PI_F * frac);
            int bin  = (int)t0f;
            int rank = offs[bin >> 6] + atomicAdd(&cursor[bin >> 6], 1);
            prow[rank] = make_float4(amp * sp, frac, amp, t0f);
        }
    }
    __syncthreads();

    for (int i = tid; i <= NB; i += 512) hdr[i] = offs[i];
}

// ===== Kernel 2: gather — LDS-staged image range, pure-VALU scan loop =======
__global__ __launch_bounds__(256)
void rir_gather_lds_kernel(const unsigned char* __restrict__ ws,
                           float* __restrict__ out_rir)
{
    __shared__ __align__(16) float4 ldsp[NIMG_TOTAL];   // 24976 B (worst range)
    __shared__ float buf[GSAMP];
    __shared__ float hann[W_LEN + 7];

    const int tid  = threadIdx.x;
    const int lane = tid & 63;
    const int w    = tid >> 6;
    const int grp  = blockIdx.x;
    const int b    = blockIdx.y;
    const int g0   = grp * GSAMP;

    const unsigned char* rowp = ws + (size_t)b * ROW_BYTES;
    const int*    hdr  = (const int*)rowp;
    const float4* prow = (const float4*)(rowp + HDR_I * 4);

    const int blo   = max(g0 - HALF_W, 0) >> 6;
    const int bhi   = min(g0 + GSAMP - 1 + HALF_W, T_LEN + HALF_W - 1) >> 6;  // <= 375
    const int start = hdr[blo];
    const int end   = hdr[bhi + 1];
    const int cnt   = end - start;

    buf[tid] = 0.0f;
    if (tid >= 128 && tid < 128 + W_LEN)
        hann[tid - 128] = 0.5f - 0.5f * __cosf((float)(tid - 128) * HSTEP);

    // ---- bulk stage: coalesced float4, all loads independent (full MLP) ----
    for (int i = tid; i < cnt; i += 256)
        ldsp[i] = prow[start + i];
    __syncthreads();

    float acc[4] = {0.f, 0.f, 0.f, 0.f};
    const float gf0 = (float)(g0 + lane);       // slots at +0, +64, +128, +192

    // ---- scan loop: wave-uniform LDS broadcast reads, no global latency ----
    #pragma unroll 4
    for (int j = w; j < cnt; j += 4) {
        float4 p = ldsp[j];                     // (asp, frac, amp, t0f)
        float n0 = gf0 - p.w;
        #pragma unroll
        for (int k = 0; k < 4; ++k) {
            float n = n0 + 64.0f * (float)k;
            if (fabsf(n) <= 40.0f) {            // <=2 of 4 can hit
                float x  = n - p.y;             // t - delay
                int   ni = (int)n;              // exact (n integer-valued)
                float sg = (ni & 1) ? p.x : -p.x;
                float v  = (x == 0.0f) ? p.z : sg * __builtin_amdgcn_rcpf(PI_F * x);
                acc[k] += v * hann[ni + HALF_W];
            }
        }
    }

    #pragma unroll
    for (int k = 0; k < 4; ++k)
        if (acc[k] != 0.0f) atomicAdd(&buf[lane + 64 * k], acc[k]);
    __syncthreads();

    const int g = g0 + tid;
    if (g < T_LEN)
        out_rir[(size_t)b * T_LEN + g] = buf[tid];
}

// ===== Fallback: R10 single-kernel (ws too small) ===========================
#define FTS 448
#define FNSLICE 54
__global__ __launch_bounds__(64)
void rir_wave_kernel(const float* __restrict__ g_in,
                     const float* __restrict__ W1, const float* __restrict__ b1,
                     const float* __restrict__ W2, const float* __restrict__ b2,
                     const float* __restrict__ W3, const float* __restrict__ b3,
                     float* __restrict__ out_rir, float* __restrict__ out_origin)
{
    __shared__ __align__(16) float rirw[FTS];
    __shared__ float dsq[3 * NK];
    __shared__ float h1[30], h2[20], zb[9], sm_in[22], rms[9];

    const int lane = threadIdx.x;
    const int s    = blockIdx.x;
    const int b    = blockIdx.y;
    const int lo   = s * FTS;
    const int nout = min(FTS, T_LEN - lo);

    float4* rir4 = (float4*)rirw;
    rir4[lane] = make_float4(0.f, 0.f, 0.f, 0.f);
    if (lane < FTS / 4 - 64) rir4[64 + lane] = make_float4(0.f, 0.f, 0.f, 0.f);

    const float c1p = PI_F * (float)(lane - HALF_W);
    const float hw1 = 0.5f - 0.5f * __cosf((float)lane * HSTEP);
    const float hw2 = 0.5f - 0.5f * __cosf((float)(lane + 64) * HSTEP);
    const float sg  = (lane & 1) ? 1.0f : -1.0f;

    if (lane < 22) sm_in[lane] = g_in[b * 22 + lane];
    if (lane < 30) {
        float a = b1[lane];
        const float* wp = W1 + lane * 22;
        #pragma unroll
        for (int i = 0; i < 22; ++i) a += sm_in[i] * wp[i];
        h1[lane] = (a >= 0.0f) ? a : NEG_SLOPE * a;
    }
    if (lane < 20) {
        float a = b2[lane];
        const float* wp = W2 + lane * 30;
        #pragma unroll
        for (int i = 0; i < 30; ++i) a += h1[i] * wp[i];
        h2[lane] = (a >= 0.0f) ? a : NEG_SLOPE * a;
    }
    if (lane < 9) {
        float a = b3[lane];
        const float* wp = W3 + lane * 20;
        #pragma unroll
        for (int i = 0; i < 20; ++i) a += h2[i] * wp[i];
        zb[lane] = 1.0f / (1.0f + __expf(-a));
    }
    if (lane < 3) {
        float room = zb[lane] * 20.0f;
        rms[lane]     = room;
        rms[3 + lane] = zb[3 + lane] * room;
        rms[6 + lane] = zb[6 + lane] * room;
    }
    if (lane == 0 && s == 0) {
        float dx = rms[3] - rms[6], dy = rms[4] - rms[7], dz = rms[5] - rms[8];
        out_origin[b] = 40.0f + FS_F * sqrtf(dx * dx + dy * dy + dz * dz) / C_F;
    }
    if (lane < 3 * NK) {
        int a  = lane / NK;
        int kk = (lane - a * NK) - MAXORD;
        float L = rms[a], src = rms[6 + a];
        float img = ((kk & 1) == 0) ? (float)kk * L + src : (float)(kk + 1) * L - src;
        float diff = img - rms[3 + a];
        dsq[lane] = diff * diff;
    }

    const float lof = (float)(lo - HALF_W);
    const float hif = (float)(lo + nout - 1 + HALF_W);

    for (int r = 0; r < NROUNDS; ++r) {
        unsigned e = g_tbl.e[r * 64 + lane];
        bool live  = (r * 64 + lane) < NIMG_TOTAL;
        int kzi = e & 31, kyi = (e >> 5) & 31, kxi = (e >> 10) & 31, order = (int)(e >> 15);
        float d    = sqrtf(dsq[kxi] + dsq[NK + kyi] + dsq[2 * NK + kzi]);
        float dlyv = 40.0f + d * FS_OVER_C;
        float t0f  = floorf(dlyv);
        float ampv = exp2f((float)order * LOG2_BETA) * INV_4PI_F
                     * __builtin_amdgcn_rcpf(fmaxf(d, 0.001f));
        bool hit = live && (t0f >= lof) && (t0f <= hif);

        unsigned long long mask = __ballot(hit);
        while (mask) {
            int l0 = __builtin_ctzll(mask); mask &= mask - 1;
            float a0 = __shfl(ampv, l0), d0 = __shfl(dlyv, l0);
            float t0b  = floorf(d0);
            float frac = d0 - t0b;
            float sp   = __sinf(PI_F * frac);
            float pv   = sg * sp;
            int   idx  = (int)t0b - HALF_W + lane - lo;
            float x1p  = c1p - PI_F * frac;
            float sv1  = (x1p == 0.0f) ? 1.0f : pv * __builtin_amdgcn_rcpf(x1p);
            if ((unsigned)idx < (unsigned)nout)
                atomicAdd(&rirw[idx], a0 * sv1 * hw1);
            if (lane < 17) {
                int idx2 = idx + 64;
                float sv2 = pv * __builtin_amdgcn_rcpf(x1p + 64.0f * PI_F);
                if ((unsigned)idx2 < (unsigned)nout)
                    atomicAdd(&rirw[idx2], a0 * sv2 * hw2);
            }
        }
    }

    const int n4 = nout / 4;
    float4* out4 = (float4*)(out_rir + (size_t)b * T_LEN + lo);
    out4[lane] = rir4[lane];
    if (lane + 64 < n4) out4[lane + 64] = rir4[lane + 64];
}

extern "C" void kernel_launch(void* const* d_in, const int* in_sizes, int n_in,
                              void* d_out, int out_size, void* d_ws, size_t ws_size,
                              hipStream_t stream) {
    const float* g_in = (const float*)d_in[0];
    const float* W1   = (const float*)d_in[1];
    const float* b1   = (const float*)d_in[2];
    const float* W2   = (const float*)d_in[3];
    const float* b2   = (const float*)d_in[4];
    const float* W3   = (const float*)d_in[5];
    const float* b3   = (const float*)d_in[6];

    const int B = in_sizes[0] / 22;

    float* out_rir    = (float*)d_out;
    float* out_origin = out_rir + (size_t)B * T_LEN;

    const size_t need_ws = (size_t)B * ROW_BYTES;   // ~3.47 MB @ B=128

    if (ws_size >= need_ws) {
        unsigned char* ws = (unsigned char*)d_ws;
        rir_prep_kernel<<<B, 512, 0, stream>>>(
            g_in, W1, b1, W2, b2, W3, b3, ws, out_origin);
        dim3 grid2(NGRP, B);
        rir_gather_lds_kernel<<<grid2, 256, 0, stream>>>(ws, out_rir);
    } else {
        dim3 grid(FNSLICE, B);
        rir_wave_kernel<<<grid, 64, 0, stream>>>(
            g_in, W1, b1, W2, b2, W3, b3, out_rir, out_origin);
    }
}